// Round 12
// baseline (240.691 us; speedup 1.0000x reference)
//
#include <hip/hip_runtime.h>
#include <hip/hip_bf16.h>

typedef float   f32x4   __attribute__((ext_vector_type(4)));
typedef __bf16  bf16x8  __attribute__((ext_vector_type(8)));
typedef unsigned short u16x8 __attribute__((ext_vector_type(8)));
typedef unsigned short u16x4 __attribute__((ext_vector_type(4)));

#define DEVI __device__ __forceinline__

DEVI unsigned short f2bf_bits(float f) {
    __bf16 h = (__bf16)f;
    return __builtin_bit_cast(unsigned short, h);
}

DEVI f32x4 mfma_bf16(bf16x8 a, bf16x8 b, f32x4 c) {
    return __builtin_amdgcn_mfma_f32_16x16x32_bf16(a, b, c, 0, 0, 0);
}

// Native v_exp_f32 (2^x); log2(e) pre-folded into Q-projection scale.
DEVI float fast_exp2(float x) {
#if __has_builtin(__builtin_amdgcn_exp2f)
    return __builtin_amdgcn_exp2f(x);
#else
    float r;
    asm("v_exp_f32 %0, %1" : "=v"(r) : "v"(x));
    return r;
#endif
}

// Async global->LDS, 16B per lane; swizzle via pre-permuted global source.
DEVI void gload16(const void* g, void* l) {
    __builtin_amdgcn_global_load_lds(
        (const __attribute__((address_space(1))) void*)g,
        (__attribute__((address_space(3))) void*)l, 16, 0, 0);
}

// ---------------------------------------------------------------------------
// W f32->bf16 pre-convert (Wq,Wk,Wv -> contiguous bf16).
// ---------------------------------------------------------------------------
__global__ __launch_bounds__(256) void convert_w_kernel(
    const float* __restrict__ Wq, const float* __restrict__ Wk,
    const float* __restrict__ Wv, unsigned short* __restrict__ Wb)
{
    int idx = blockIdx.x * 256 + threadIdx.x;
    int which = idx >> 17;
    int off = (idx & 131071) * 8;
    const float* src = which == 0 ? Wq : (which == 1 ? Wk : Wv);
    f32x4 a = *(const f32x4*)(src + off);
    f32x4 b = *(const f32x4*)(src + off + 4);
    u16x8 h;
#pragma unroll
    for (int j = 0; j < 4; ++j) { h[j] = f2bf_bits(a[j]); h[4 + j] = f2bf_bits(b[j]); }
    *(u16x8*)(Wb + (size_t)which * 1048576 + off) = h;
}

// ---------------------------------------------------------------------------
// Merged QKV projection. Grid (x=rowblk 64, y=proj 3, z=colblk 8); x varies
// FASTEST, so each run of 64 consecutive blocks shares one 256KB W panel
// (L2-resident, like the split dispatches) while the merge lifts blocks/CU
// from 2 to ~5. R5's merge failed because its ordering varied the panel
// fastest (24 panels co-resident = 6MB > 4MB L2 -> FETCH 400MB).
// Body: W=bf16 via global_load_lds (pre-swizzled source); A=f32 T14
// async-split reg-staging with inline bf16 convert.
// ---------------------------------------------------------------------------
__global__ __launch_bounds__(256) void qkv_gemm_kernel(
    const float* __restrict__ q, const float* __restrict__ k, const float* __restrict__ v,
    const unsigned short* __restrict__ Wbf,
    const float* __restrict__ bq, const float* __restrict__ bk, const float* __restrict__ bv,
    unsigned short* __restrict__ Qp, unsigned short* __restrict__ Kp, unsigned short* __restrict__ Vp,
    float qscale)
{
    __shared__ __align__(16) char ldsA[128 * 128];
    __shared__ __align__(16) char ldsB[128 * 128];
    const int t = threadIdx.x;
    const int wave = t >> 6, lane = t & 63;
    const int g = lane >> 4, c = lane & 15;
    const int proj = blockIdx.y;
    const int rowbase = blockIdx.x * 128;
    const int colbase = blockIdx.z * 128;
    const int wr = (wave >> 1) * 64, wc = (wave & 1) * 64;
    const int K = 1024;

    const float* A    = proj == 0 ? q  : (proj == 1 ? k  : v);
    const float* bias = proj == 0 ? bq : (proj == 1 ? bk : bv);
    unsigned short* C = proj == 0 ? Qp : (proj == 1 ? Kp : Vp);
    const unsigned short* Wb = Wbf + (size_t)proj * 1048576;
    const float scale = proj == 0 ? qscale : 1.0f;

    const int arow = lane >> 3;
    const int aslot = (lane & 7) ^ arow;

    const float* fbase[4];
#pragma unroll
    for (int ch = 0; ch < 4; ++ch) {
        int id = ch * 256 + t;
        int row = id >> 3;
        int col = (id & 7) * 8;
        fbase[ch] = A + (size_t)(rowbase + row) * K + col;
    }

    f32x4 pre0[4], pre1[4];
#pragma unroll
    for (int ch = 0; ch < 4; ++ch) {
        pre0[ch] = *(const f32x4*)(fbase[ch]);
        pre1[ch] = *(const f32x4*)(fbase[ch] + 4);
    }

    f32x4 acc[4][4] = {};

    for (int kt = 0; kt < K; kt += 64) {
#pragma unroll
        for (int j = 0; j < 4; ++j) {
            int rg = wave * 4 + j;
            int row = rg * 8 + arow;
            gload16(Wb + (size_t)(colbase + row) * K + kt + aslot * 8,
                    ldsB + rg * 1024);
        }

#pragma unroll
        for (int ch = 0; ch < 4; ++ch) {
            int id = ch * 256 + t;
            int row = id >> 3;
            int col = (id & 7) * 8;
            int dst = row * 128 + ((col * 2) ^ ((row & 7) << 4));
            u16x8 hv;
#pragma unroll
            for (int j = 0; j < 4; ++j) { hv[j] = f2bf_bits(pre0[ch][j]); hv[4 + j] = f2bf_bits(pre1[ch][j]); }
            *(u16x8*)(ldsA + dst) = hv;
        }
        __syncthreads();

        if (kt + 64 < K) {
#pragma unroll
            for (int ch = 0; ch < 4; ++ch) {
                pre0[ch] = *(const f32x4*)(fbase[ch] + kt + 64);
                pre1[ch] = *(const f32x4*)(fbase[ch] + kt + 68);
            }
        }

#pragma unroll
        for (int kk = 0; kk < 2; ++kk) {
            bf16x8 af[4], bfr[4];
#pragma unroll
            for (int i = 0; i < 4; ++i) {
                int ra = wr + i * 16 + c;
                af[i] = *(const bf16x8*)(ldsA + ra * 128 + ((kk * 64 + g * 16) ^ ((ra & 7) << 4)));
                int rb = wc + i * 16 + c;
                bfr[i] = *(const bf16x8*)(ldsB + rb * 128 + ((kk * 64 + g * 16) ^ ((rb & 7) << 4)));
            }
#pragma unroll
            for (int i = 0; i < 4; ++i)
#pragma unroll
                for (int j = 0; j < 4; ++j)
                    acc[i][j] = mfma_bf16(af[i], bfr[j], acc[i][j]);
        }
        __syncthreads();
    }

#pragma unroll
    for (int j = 0; j < 4; ++j) {
        int coln = colbase + wc + j * 16 + c;
        float bv2 = bias[coln];
#pragma unroll
        for (int i = 0; i < 4; ++i) {
            int row0 = rowbase + wr + i * 16 + g * 4;
#pragma unroll
            for (int r = 0; r < 4; ++r) {
                float val = (acc[i][j][r] + bv2) * scale;
                C[(size_t)(row0 + r) * 1024 + coln] = f2bf_bits(val);
            }
        }
    }
}

// ---------------------------------------------------------------------------
// GEMM for the output projection: A=bf16 gload_lds, W=f32 T14 reg-staged.
// ---------------------------------------------------------------------------
__global__ __launch_bounds__(256) void out_gemm_kernel(
    const unsigned short* __restrict__ Ab, const float* __restrict__ W,
    const float* __restrict__ bias, float* __restrict__ Cp,
    int M, int N, int K)
{
    __shared__ __align__(16) char ldsA[128 * 128];
    __shared__ __align__(16) char ldsB[128 * 128];
    const int t = threadIdx.x;
    const int wave = t >> 6, lane = t & 63;
    const int g = lane >> 4, c = lane & 15;
    const int rowbase = blockIdx.x * 128;
    const int colbase = blockIdx.y * 128;
    const int wr = (wave >> 1) * 64, wc = (wave & 1) * 64;

    const int arow = lane >> 3;
    const int aslot = (lane & 7) ^ arow;

    const float* fbase[4];
#pragma unroll
    for (int ch = 0; ch < 4; ++ch) {
        int id = ch * 256 + t;
        int row = id >> 3;
        int col = (id & 7) * 8;
        fbase[ch] = W + (size_t)(colbase + row) * K + col;
    }

    f32x4 pre0[4], pre1[4];
#pragma unroll
    for (int ch = 0; ch < 4; ++ch) {
        pre0[ch] = *(const f32x4*)(fbase[ch]);
        pre1[ch] = *(const f32x4*)(fbase[ch] + 4);
    }

    f32x4 acc[4][4] = {};

    for (int kt = 0; kt < K; kt += 64) {
#pragma unroll
        for (int j = 0; j < 4; ++j) {
            int rg = wave * 4 + j;
            int row = rg * 8 + arow;
            gload16(Ab + (size_t)(rowbase + row) * K + kt + aslot * 8,
                    ldsA + rg * 1024);
        }

#pragma unroll
        for (int ch = 0; ch < 4; ++ch) {
            int id = ch * 256 + t;
            int row = id >> 3;
            int col = (id & 7) * 8;
            int dst = row * 128 + ((col * 2) ^ ((row & 7) << 4));
            u16x8 hv;
#pragma unroll
            for (int j = 0; j < 4; ++j) { hv[j] = f2bf_bits(pre0[ch][j]); hv[4 + j] = f2bf_bits(pre1[ch][j]); }
            *(u16x8*)(ldsB + dst) = hv;
        }
        __syncthreads();

        if (kt + 64 < K) {
#pragma unroll
            for (int ch = 0; ch < 4; ++ch) {
                pre0[ch] = *(const f32x4*)(fbase[ch] + kt + 64);
                pre1[ch] = *(const f32x4*)(fbase[ch] + kt + 68);
            }
        }

#pragma unroll
        for (int kk = 0; kk < 2; ++kk) {
            bf16x8 af[4], bfr[4];
#pragma unroll
            for (int i = 0; i < 4; ++i) {
                int ra = wr + i * 16 + c;
                af[i] = *(const bf16x8*)(ldsA + ra * 128 + ((kk * 64 + g * 16) ^ ((ra & 7) << 4)));
                int rb = wc + i * 16 + c;
                bfr[i] = *(const bf16x8*)(ldsB + rb * 128 + ((kk * 64 + g * 16) ^ ((rb & 7) << 4)));
            }
#pragma unroll
            for (int i = 0; i < 4; ++i)
#pragma unroll
                for (int j = 0; j < 4; ++j)
                    acc[i][j] = mfma_bf16(af[i], bfr[j], acc[i][j]);
        }
        __syncthreads();
    }

#pragma unroll
    for (int j = 0; j < 4; ++j) {
        int coln = colbase + wc + j * 16 + c;
        float bv = bias[coln];
#pragma unroll
        for (int i = 0; i < 4; ++i) {
            int row0 = rowbase + wr + i * 16 + g * 4;
#pragma unroll
            for (int r = 0; r < 4; ++r)
                Cp[(size_t)(row0 + r) * N + coln] = acc[i][j][r] + bv;
        }
    }
}

// ---------------------------------------------------------------------------
// Transpose Vp[B,S,D] (head-sliced) -> Vt[B,H,hd,S].
// ---------------------------------------------------------------------------
__global__ __launch_bounds__(256) void transpose_v_kernel(
    const unsigned short* __restrict__ Vp, unsigned short* __restrict__ Vt)
{
    __shared__ unsigned short tile[64][72];
    const int t = threadIdx.x;
    const int bh = blockIdx.y, b = bh >> 4, h = bh & 15;
    const int s0 = blockIdx.x * 64;
#pragma unroll
    for (int ch = 0; ch < 2; ++ch) {
        int id = ch * 256 + t;
        int srow = id >> 3, dcol = (id & 7) * 8;
        u16x8 v = *(const u16x8*)(Vp + (size_t)(b * 2048 + s0 + srow) * 1024 + h * 64 + dcol);
        *(u16x8*)&tile[srow][dcol] = v;
    }
    __syncthreads();
#pragma unroll
    for (int ch = 0; ch < 2; ++ch) {
        int id = ch * 256 + t;
        int drow = id >> 3, scol = (id & 7) * 8;
        u16x8 ov;
#pragma unroll
        for (int j = 0; j < 8; ++j) ov[j] = tile[scol + j][drow];
        *(u16x8*)(Vt + (size_t)(bh * 64 + drow) * 2048 + s0 + scol) = ov;
    }
}

// ---------------------------------------------------------------------------
// Flash attention — R10 version (known-good 99us). Grid (S/128, B*H) = 1024
// blocks = 4/CU; R11 showed 2 q-sets is the TLP/traffic sweet spot (4 q-sets
// halved occupancy 24->10.6%, 99->110us). 4 waves x 32 q-rows (2 q-sets).
// P = fast_exp2(S); fixed-max softmax; swapped QK^T; packed P writes;
// async-STAGE prefetch. No setprio (R6).
// ---------------------------------------------------------------------------
__global__ __launch_bounds__(256) void attn_kernel(
    const unsigned short* __restrict__ Qp, const unsigned short* __restrict__ Kp,
    const unsigned short* __restrict__ Vt, unsigned short* __restrict__ ctx)
{
    __shared__ __align__(16) char ldsK[64 * 128];
    __shared__ __align__(16) char ldsV[64 * 128];
    __shared__ __align__(16) char ldsP[4][2][16 * 128];
    const int t = threadIdx.x;
    const int wave = t >> 6, lane = t & 63;
    const int g = lane >> 4, c = lane & 15;
    const int bh = blockIdx.y, b = bh >> 4, h = bh & 15;
    const int qb = blockIdx.x * 128;

    bf16x8 qf0[2], qf1[2];
    {
        const unsigned short* q0 = Qp + (size_t)(b * 2048 + qb + wave * 32 + c) * 1024 + h * 64;
        qf0[0] = *(const bf16x8*)(q0 + 8 * g);
        qf0[1] = *(const bf16x8*)(q0 + 32 + 8 * g);
        const unsigned short* q1 = q0 + (size_t)16 * 1024;
        qf1[0] = *(const bf16x8*)(q1 + 8 * g);
        qf1[1] = *(const bf16x8*)(q1 + 32 + 8 * g);
    }

    f32x4 o0[4] = {}, o1[4] = {};
    float psum0 = 0.f, psum1 = 0.f;

    const int row0 = t >> 3, colB = (t & 7) * 8;
    const int row1 = 32 + row0;
    const int dst0 = row0 * 128 + ((colB * 2) ^ ((row0 & 7) << 4));
    const int dst1 = row1 * 128 + ((colB * 2) ^ ((row1 & 7) << 4));
    const unsigned short* Ksrc = Kp + (size_t)(b * 2048) * 1024 + h * 64;
    const unsigned short* Vsrc = Vt + (size_t)(bh * 64) * 2048;

    u16x8 kv0 = *(const u16x8*)(Ksrc + (size_t)row0 * 1024 + colB);
    u16x8 kv1 = *(const u16x8*)(Ksrc + (size_t)row1 * 1024 + colB);
    u16x8 vv0 = *(const u16x8*)(Vsrc + (size_t)row0 * 2048 + colB);
    u16x8 vv1 = *(const u16x8*)(Vsrc + (size_t)row1 * 2048 + colB);

    char* pw0 = ldsP[wave][0];
    char* pw1 = ldsP[wave][1];

    for (int kb = 0; kb < 2048; kb += 64) {
        *(u16x8*)(ldsK + dst0) = kv0;
        *(u16x8*)(ldsK + dst1) = kv1;
        *(u16x8*)(ldsV + dst0) = vv0;
        *(u16x8*)(ldsV + dst1) = vv1;
        __syncthreads();

        if (kb + 64 < 2048) {
            kv0 = *(const u16x8*)(Ksrc + (size_t)(kb + 64 + row0) * 1024 + colB);
            kv1 = *(const u16x8*)(Ksrc + (size_t)(kb + 64 + row1) * 1024 + colB);
            vv0 = *(const u16x8*)(Vsrc + (size_t)row0 * 2048 + kb + 64 + colB);
            vv1 = *(const u16x8*)(Vsrc + (size_t)row1 * 2048 + kb + 64 + colB);
        }

        f32x4 s0[4] = {}, s1[4] = {};
#pragma unroll
        for (int kk = 0; kk < 2; ++kk) {
            bf16x8 kf[4];
#pragma unroll
            for (int ti = 0; ti < 4; ++ti) {
                int rk = ti * 16 + c;
                kf[ti] = *(const bf16x8*)(ldsK + rk * 128 + ((kk * 64 + g * 16) ^ ((rk & 7) << 4)));
            }
#pragma unroll
            for (int ti = 0; ti < 4; ++ti) {
                s0[ti] = mfma_bf16(kf[ti], qf0[kk], s0[ti]);
                s1[ti] = mfma_bf16(kf[ti], qf1[kk], s1[ti]);
            }
        }

#pragma unroll
        for (int ti = 0; ti < 4; ++ti) {
            float p0 = fast_exp2(s0[ti][0]);
            float p1 = fast_exp2(s0[ti][1]);
            float p2 = fast_exp2(s0[ti][2]);
            float p3 = fast_exp2(s0[ti][3]);
            psum0 += (p0 + p1) + (p2 + p3);
            u16x4 hp;
            hp[0] = f2bf_bits(p0); hp[1] = f2bf_bits(p1);
            hp[2] = f2bf_bits(p2); hp[3] = f2bf_bits(p3);
            *(u16x4*)(pw0 + c * 128 + ((ti * 32 + g * 8) ^ ((c & 7) << 4))) = hp;
        }
#pragma unroll
        for (int ti = 0; ti < 4; ++ti) {
            float p0 = fast_exp2(s1[ti][0]);
            float p1 = fast_exp2(s1[ti][1]);
            float p2 = fast_exp2(s1[ti][2]);
            float p3 = fast_exp2(s1[ti][3]);
            psum1 += (p0 + p1) + (p2 + p3);
            u16x4 hp;
            hp[0] = f2bf_bits(p0); hp[1] = f2bf_bits(p1);
            hp[2] = f2bf_bits(p2); hp[3] = f2bf_bits(p3);
            *(u16x4*)(pw1 + c * 128 + ((ti * 32 + g * 8) ^ ((c & 7) << 4))) = hp;
        }

#pragma unroll
        for (int kk = 0; kk < 2; ++kk) {
            bf16x8 vf[4];
#pragma unroll
            for (int ti = 0; ti < 4; ++ti) {
                int rv = ti * 16 + c;
                vf[ti] = *(const bf16x8*)(ldsV + rv * 128 + ((kk * 64 + g * 16) ^ ((rv & 7) << 4)));
            }
            bf16x8 pa0 = *(const bf16x8*)(pw0 + c * 128 + ((kk * 64 + g * 16) ^ ((c & 7) << 4)));
            bf16x8 pa1 = *(const bf16x8*)(pw1 + c * 128 + ((kk * 64 + g * 16) ^ ((c & 7) << 4)));
#pragma unroll
            for (int ti = 0; ti < 4; ++ti) {
                o0[ti] = mfma_bf16(pa0, vf[ti], o0[ti]);
                o1[ti] = mfma_bf16(pa1, vf[ti], o1[ti]);
            }
        }
        __syncthreads();
    }

    psum0 += __shfl_xor(psum0, 16);
    psum0 += __shfl_xor(psum0, 32);
    psum1 += __shfl_xor(psum1, 16);
    psum1 += __shfl_xor(psum1, 32);

#pragma unroll
    for (int r = 0; r < 4; ++r) {
        float inv0 = 1.0f / __shfl(psum0, 4 * g + r);
        float inv1 = 1.0f / __shfl(psum1, 4 * g + r);
        int row0q = qb + wave * 32 + 4 * g + r;
        int row1q = row0q + 16;
#pragma unroll
        for (int ti = 0; ti < 4; ++ti) {
            int col = h * 64 + ti * 16 + c;
            ctx[(size_t)(b * 2048 + row0q) * 1024 + col] = f2bf_bits(o0[ti][r] * inv0);
            ctx[(size_t)(b * 2048 + row1q) * 1024 + col] = f2bf_bits(o1[ti][r] * inv1);
        }
    }
}

// ---------------------------------------------------------------------------
extern "C" void kernel_launch(void* const* d_in, const int* in_sizes, int n_in,
                              void* d_out, int out_size, void* d_ws, size_t ws_size,
                              hipStream_t stream)
{
    const float* q  = (const float*)d_in[0];
    const float* k  = (const float*)d_in[1];
    const float* v  = (const float*)d_in[2];
    const float* Wq = (const float*)d_in[3];
    const float* bq = (const float*)d_in[4];
    const float* Wk = (const float*)d_in[5];
    const float* bk = (const float*)d_in[6];
    const float* Wv = (const float*)d_in[7];
    const float* bv = (const float*)d_in[8];
    const float* Wo = (const float*)d_in[9];
    const float* bo = (const float*)d_in[10];
    float* out = (float*)d_out;

    char* ws = (char*)d_ws;
    const size_t SZ = (size_t)8192 * 1024 * 2; // 16 MiB per bf16 [M,D] buffer
    unsigned short* Qp = (unsigned short*)(ws);
    unsigned short* Kp = (unsigned short*)(ws + SZ);
    unsigned short* Vp = (unsigned short*)(ws + 2 * SZ);
    unsigned short* Vt = (unsigned short*)(ws + 3 * SZ);
    unsigned short* ctx = Vp;  // Vp dead after transpose; reuse for ctx
    unsigned short* Wbf = Vt;  // W bf16 parked in Vt region (dead until transpose)

    const float QSCALE = 0.1803368801111244f; // 0.125 * log2(e) for exp2 attn

    convert_w_kernel<<<dim3(1536), 256, 0, stream>>>(Wq, Wk, Wv, Wbf);
    qkv_gemm_kernel<<<dim3(64, 3, 8), 256, 0, stream>>>(
        q, k, v, Wbf, bq, bk, bv, Qp, Kp, Vp, QSCALE);
    transpose_v_kernel<<<dim3(32, 64), 256, 0, stream>>>(Vp, Vt);
    attn_kernel<<<dim3(16, 64), 256, 0, stream>>>(Qp, Kp, Vt, ctx);
    out_gemm_kernel<<<dim3(64, 8), 256, 0, stream>>>(ctx, Wo, bo, out, 8192, 1024, 1024);
}

// Round 13
// 232.002 us; speedup vs baseline: 1.0375x; 1.0375x over previous
//
#include <hip/hip_runtime.h>
#include <hip/hip_bf16.h>

typedef float   f32x4   __attribute__((ext_vector_type(4)));
typedef float   f32x16  __attribute__((ext_vector_type(16)));
typedef __bf16  bf16x8  __attribute__((ext_vector_type(8)));
typedef unsigned short u16x8 __attribute__((ext_vector_type(8)));
typedef unsigned short u16x4 __attribute__((ext_vector_type(4)));
typedef unsigned int   u32x4v __attribute__((ext_vector_type(4)));

#define DEVI __device__ __forceinline__

DEVI unsigned short f2bf_bits(float f) {
    __bf16 h = (__bf16)f;
    return __builtin_bit_cast(unsigned short, h);
}

DEVI f32x4 mfma_bf16(bf16x8 a, bf16x8 b, f32x4 c) {
    return __builtin_amdgcn_mfma_f32_16x16x32_bf16(a, b, c, 0, 0, 0);
}

DEVI f32x16 mfma32(bf16x8 a, bf16x8 b, f32x16 c) {
    return __builtin_amdgcn_mfma_f32_32x32x16_bf16(a, b, c, 0, 0, 0);
}

// Native v_exp_f32 (2^x); log2(e) pre-folded into Q-projection scale.
DEVI float fast_exp2(float x) {
#if __has_builtin(__builtin_amdgcn_exp2f)
    return __builtin_amdgcn_exp2f(x);
#else
    float r;
    asm("v_exp_f32 %0, %1" : "=v"(r) : "v"(x));
    return r;
#endif
}

// dst = [bf16(lo) | bf16(hi)] packed in one u32 (RNE).
DEVI unsigned int cvt_pk_bf16(float lo, float hi) {
    unsigned int r;
    asm("v_cvt_pk_bf16_f32 %0, %1, %2" : "=v"(r) : "v"(lo), "v"(hi));
    return r;
}

// x' = [x_lo | y_lo], y' = [x_hi | y_hi]  (lane-half exchange, VALU pipe).
DEVI void permlane32_swap(unsigned int& x, unsigned int& y) {
    asm("v_permlane32_swap_b32 %0, %1" : "+v"(x), "+v"(y));
}

// Async global->LDS, 16B per lane; swizzle via pre-permuted global source.
DEVI void gload16(const void* g, void* l) {
    __builtin_amdgcn_global_load_lds(
        (const __attribute__((address_space(1))) void*)g,
        (__attribute__((address_space(3))) void*)l, 16, 0, 0);
}

// ---------------------------------------------------------------------------
// W f32->bf16 pre-convert (Wq,Wk,Wv -> contiguous bf16).
// ---------------------------------------------------------------------------
__global__ __launch_bounds__(256) void convert_w_kernel(
    const float* __restrict__ Wq, const float* __restrict__ Wk,
    const float* __restrict__ Wv, unsigned short* __restrict__ Wb)
{
    int idx = blockIdx.x * 256 + threadIdx.x;
    int which = idx >> 17;
    int off = (idx & 131071) * 8;
    const float* src = which == 0 ? Wq : (which == 1 ? Wk : Wv);
    f32x4 a = *(const f32x4*)(src + off);
    f32x4 b = *(const f32x4*)(src + off + 4);
    u16x8 h;
#pragma unroll
    for (int j = 0; j < 4; ++j) { h[j] = f2bf_bits(a[j]); h[4 + j] = f2bf_bits(b[j]); }
    *(u16x8*)(Wb + (size_t)which * 1048576 + off) = h;
}

// ---------------------------------------------------------------------------
// GEMM: C[M,N] = A[M,K] @ W[N,K]^T + bias, scale on (val+bias). R10 version.
// SPLIT dispatch per projection is structurally required: merged QKV makes
// ~1280 blocks co-resident whose per-XCD W working set (6MB) exceeds the 4MB
// L2 -> thrash (R5: FETCH 400MB; R12: 130us vs 87us split). Ordering can't
// fix co-residency.
//   A_ASYNC=false: A=f32 T14 reg-staged, W=bf16 gload_lds  (projections)
//   A_ASYNC=true : A=bf16 gload_lds,  W=f32 T14 reg-staged (out-proj)
// ---------------------------------------------------------------------------
template <bool A_ASYNC, bool OUT_F32>
__global__ __launch_bounds__(256) void gemm_bt_kernel(
    const void* __restrict__ Ap, const void* __restrict__ Wp,
    const float* __restrict__ bias, void* __restrict__ Cp,
    int M, int N, int K, float scale)
{
    __shared__ __align__(16) char ldsA[128 * 128];
    __shared__ __align__(16) char ldsB[128 * 128];
    const int t = threadIdx.x;
    const int wave = t >> 6, lane = t & 63;
    const int g = lane >> 4, c = lane & 15;
    const int rowbase = blockIdx.x * 128;
    const int colbase = blockIdx.y * 128;
    const int wr = (wave >> 1) * 64, wc = (wave & 1) * 64;

    const int arow = lane >> 3;
    const int aslot = (lane & 7) ^ arow;

    const float* fbase[4];
#pragma unroll
    for (int ch = 0; ch < 4; ++ch) {
        int id = ch * 256 + t;
        int row = id >> 3;
        int col = (id & 7) * 8;
        if constexpr (A_ASYNC)
            fbase[ch] = (const float*)Wp + (size_t)(colbase + row) * K + col;
        else
            fbase[ch] = (const float*)Ap + (size_t)(rowbase + row) * K + col;
    }

    f32x4 pre0[4], pre1[4];
#pragma unroll
    for (int ch = 0; ch < 4; ++ch) {
        pre0[ch] = *(const f32x4*)(fbase[ch]);
        pre1[ch] = *(const f32x4*)(fbase[ch] + 4);
    }

    f32x4 acc[4][4] = {};

    for (int kt = 0; kt < K; kt += 64) {
        if constexpr (A_ASYNC) {
            const unsigned short* Ab = (const unsigned short*)Ap;
#pragma unroll
            for (int j = 0; j < 4; ++j) {
                int rg = wave * 4 + j;
                int row = rg * 8 + arow;
                gload16(Ab + (size_t)(rowbase + row) * K + kt + aslot * 8,
                        ldsA + rg * 1024);
            }
        } else {
            const unsigned short* Wb = (const unsigned short*)Wp;
#pragma unroll
            for (int j = 0; j < 4; ++j) {
                int rg = wave * 4 + j;
                int row = rg * 8 + arow;
                gload16(Wb + (size_t)(colbase + row) * K + kt + aslot * 8,
                        ldsB + rg * 1024);
            }
        }

#pragma unroll
        for (int ch = 0; ch < 4; ++ch) {
            int id = ch * 256 + t;
            int row = id >> 3;
            int col = (id & 7) * 8;
            int dst = row * 128 + ((col * 2) ^ ((row & 7) << 4));
            u16x8 hv;
#pragma unroll
            for (int j = 0; j < 4; ++j) { hv[j] = f2bf_bits(pre0[ch][j]); hv[4 + j] = f2bf_bits(pre1[ch][j]); }
            if constexpr (A_ASYNC)
                *(u16x8*)(ldsB + dst) = hv;
            else
                *(u16x8*)(ldsA + dst) = hv;
        }
        __syncthreads();

        if (kt + 64 < K) {
#pragma unroll
            for (int ch = 0; ch < 4; ++ch) {
                pre0[ch] = *(const f32x4*)(fbase[ch] + kt + 64);
                pre1[ch] = *(const f32x4*)(fbase[ch] + kt + 68);
            }
        }

#pragma unroll
        for (int kk = 0; kk < 2; ++kk) {
            bf16x8 af[4], bfr[4];
#pragma unroll
            for (int i = 0; i < 4; ++i) {
                int ra = wr + i * 16 + c;
                af[i] = *(const bf16x8*)(ldsA + ra * 128 + ((kk * 64 + g * 16) ^ ((ra & 7) << 4)));
                int rb = wc + i * 16 + c;
                bfr[i] = *(const bf16x8*)(ldsB + rb * 128 + ((kk * 64 + g * 16) ^ ((rb & 7) << 4)));
            }
#pragma unroll
            for (int i = 0; i < 4; ++i)
#pragma unroll
                for (int j = 0; j < 4; ++j)
                    acc[i][j] = mfma_bf16(af[i], bfr[j], acc[i][j]);
        }
        __syncthreads();
    }

#pragma unroll
    for (int j = 0; j < 4; ++j) {
        int coln = colbase + wc + j * 16 + c;
        float bv = bias[coln];
#pragma unroll
        for (int i = 0; i < 4; ++i) {
            int row0 = rowbase + wr + i * 16 + g * 4;
#pragma unroll
            for (int r = 0; r < 4; ++r) {
                float val = (acc[i][j][r] + bv) * scale;
                if constexpr (OUT_F32)
                    ((float*)Cp)[(size_t)(row0 + r) * N + coln] = val;
                else
                    ((unsigned short*)Cp)[(size_t)(row0 + r) * N + coln] = f2bf_bits(val);
            }
        }
    }
}

// ---------------------------------------------------------------------------
// Transpose Vp[B,S,D] (head-sliced) -> Vt[B,H,hd,S].
// ---------------------------------------------------------------------------
__global__ __launch_bounds__(256) void transpose_v_kernel(
    const unsigned short* __restrict__ Vp, unsigned short* __restrict__ Vt)
{
    __shared__ unsigned short tile[64][72];
    const int t = threadIdx.x;
    const int bh = blockIdx.y, b = bh >> 4, h = bh & 15;
    const int s0 = blockIdx.x * 64;
#pragma unroll
    for (int ch = 0; ch < 2; ++ch) {
        int id = ch * 256 + t;
        int srow = id >> 3, dcol = (id & 7) * 8;
        u16x8 v = *(const u16x8*)(Vp + (size_t)(b * 2048 + s0 + srow) * 1024 + h * 64 + dcol);
        *(u16x8*)&tile[srow][dcol] = v;
    }
    __syncthreads();
#pragma unroll
    for (int ch = 0; ch < 2; ++ch) {
        int id = ch * 256 + t;
        int drow = id >> 3, scol = (id & 7) * 8;
        u16x8 ov;
#pragma unroll
        for (int j = 0; j < 8; ++j) ov[j] = tile[scol + j][drow];
        *(u16x8*)(Vt + (size_t)(bh * 64 + drow) * 2048 + s0 + scol) = ov;
    }
}

// ---------------------------------------------------------------------------
// Flash attention, 32x32-MFMA + in-register P. Grid (S/128, B*H) = 1024
// blocks (R10's proven occupancy shape). 4 waves x 32 q-rows.
// R10 measured at the LDS-BW roofline (112KB/tile, 7.3GB ~ 99us @69TB/s).
// This version deletes the P LDS round-trip (32KB/tile): swapped QK^T via
// mfma_32x32x16 leaves S^T with col=qrow=lane&31, row=key=(reg&3)+8(reg>>2)
// +4*(lane>>5) [guide m74/m101]; the PV A-frag (row=qrow, k=key=8(lane>>5)+j)
// then needs exactly a lane<->lane+32 exchange: cvt_pk_bf16 pairs +
// v_permlane32_swap_b32 (x'=[x_lo|y_lo], y'=[x_hi|y_hi]) build pa in-register.
// New traffic: 16 staging + 32 K-frag + 32 V-frag = 80KB/tile (~71us floor).
// LDS 16KB/block. Fixed-max softmax, fast_exp2, T14 prefetch, no setprio.
// ---------------------------------------------------------------------------
__global__ __launch_bounds__(256) void attn_kernel(
    const unsigned short* __restrict__ Qp, const unsigned short* __restrict__ Kp,
    const unsigned short* __restrict__ Vt, unsigned short* __restrict__ ctx)
{
    __shared__ __align__(16) char ldsK[64 * 128];   // [key][hd] swizzled
    __shared__ __align__(16) char ldsV[64 * 128];   // [hd][key] swizzled
    const int t = threadIdx.x;
    const int wave = t >> 6, lane = t & 63;
    const int q32 = lane & 31, hi = lane >> 5;
    const int bh = blockIdx.y, b = bh >> 4, h = bh & 15;
    const int qb = blockIdx.x * 128;

    // Q B-frags: row=q32 (qrow), k = 16ks + 8hi + j
    bf16x8 qf[4];
    {
        const unsigned short* qrowp = Qp + (size_t)(b * 2048 + qb + wave * 32 + q32) * 1024 + h * 64;
#pragma unroll
        for (int ks = 0; ks < 4; ++ks)
            qf[ks] = *(const bf16x8*)(qrowp + 16 * ks + 8 * hi);
    }

    f32x16 o0 = {}, o1 = {};    // O[qrow][hd], hd blocks 0-31 / 32-63
    float psum = 0.f;

    const int row0 = t >> 3, colB = (t & 7) * 8;
    const int row1 = 32 + row0;
    const int dst0 = row0 * 128 + ((colB * 2) ^ ((row0 & 7) << 4));
    const int dst1 = row1 * 128 + ((colB * 2) ^ ((row1 & 7) << 4));
    const unsigned short* Ksrc = Kp + (size_t)(b * 2048) * 1024 + h * 64;
    const unsigned short* Vsrc = Vt + (size_t)(bh * 64) * 2048;

    u16x8 kv0 = *(const u16x8*)(Ksrc + (size_t)row0 * 1024 + colB);
    u16x8 kv1 = *(const u16x8*)(Ksrc + (size_t)row1 * 1024 + colB);
    u16x8 vv0 = *(const u16x8*)(Vsrc + (size_t)row0 * 2048 + colB);
    u16x8 vv1 = *(const u16x8*)(Vsrc + (size_t)row1 * 2048 + colB);

    for (int kb = 0; kb < 2048; kb += 64) {
        *(u16x8*)(ldsK + dst0) = kv0;
        *(u16x8*)(ldsK + dst1) = kv1;
        *(u16x8*)(ldsV + dst0) = vv0;
        *(u16x8*)(ldsV + dst1) = vv1;
        __syncthreads();

        if (kb + 64 < 2048) {
            kv0 = *(const u16x8*)(Ksrc + (size_t)(kb + 64 + row0) * 1024 + colB);
            kv1 = *(const u16x8*)(Ksrc + (size_t)(kb + 64 + row1) * 1024 + colB);
            vv0 = *(const u16x8*)(Vsrc + (size_t)row0 * 2048 + kb + 64 + colB);
            vv1 = *(const u16x8*)(Vsrc + (size_t)row1 * 2048 + kb + 64 + colB);
        }

        // S^T = K Q^T : s0 = keys 0-31, s1 = keys 32-63 (cols = qrow)
        f32x16 s0 = {}, s1 = {};
#pragma unroll
        for (int ks = 0; ks < 4; ++ks) {
            int rk0 = q32;
            bf16x8 kf0 = *(const bf16x8*)(ldsK + rk0 * 128 + ((ks * 32 + 16 * hi) ^ ((rk0 & 7) << 4)));
            s0 = mfma32(kf0, qf[ks], s0);
            int rk1 = 32 + q32;
            bf16x8 kf1 = *(const bf16x8*)(ldsK + rk1 * 128 + ((ks * 32 + 16 * hi) ^ ((rk1 & 7) << 4)));
            s1 = mfma32(kf1, qf[ks], s1);
        }

        // P = exp2(S); psum lane-local (this lane's keys for qrow=q32)
#pragma unroll
        for (int r = 0; r < 16; ++r) { s0[r] = fast_exp2(s0[r]); psum += s0[r]; }
#pragma unroll
        for (int r = 0; r < 16; ++r) { s1[r] = fast_exp2(s1[r]); psum += s1[r]; }

        // O += P V : pa built in-register per 16-key step (no LDS)
#pragma unroll
        for (int ks = 0; ks < 4; ++ks) {
            int r0 = (ks & 1) * 8;
            unsigned int x0, x1, y0, y1;
            if (ks < 2) {
                x0 = cvt_pk_bf16(s0[r0],     s0[r0 + 1]);
                x1 = cvt_pk_bf16(s0[r0 + 2], s0[r0 + 3]);
                y0 = cvt_pk_bf16(s0[r0 + 4], s0[r0 + 5]);
                y1 = cvt_pk_bf16(s0[r0 + 6], s0[r0 + 7]);
            } else {
                x0 = cvt_pk_bf16(s1[r0],     s1[r0 + 1]);
                x1 = cvt_pk_bf16(s1[r0 + 2], s1[r0 + 3]);
                y0 = cvt_pk_bf16(s1[r0 + 4], s1[r0 + 5]);
                y1 = cvt_pk_bf16(s1[r0 + 6], s1[r0 + 7]);
            }
            permlane32_swap(x0, y0);
            permlane32_swap(x1, y1);
            u32x4v pw; pw[0] = x0; pw[1] = x1; pw[2] = y0; pw[3] = y1;
            bf16x8 pa = __builtin_bit_cast(bf16x8, pw);

            int rv0 = q32;
            bf16x8 vf0 = *(const bf16x8*)(ldsV + rv0 * 128 + ((ks * 32 + 16 * hi) ^ ((rv0 & 7) << 4)));
            o0 = mfma32(pa, vf0, o0);
            int rv1 = 32 + q32;
            bf16x8 vf1 = *(const bf16x8*)(ldsV + rv1 * 128 + ((ks * 32 + 16 * hi) ^ ((rv1 & 7) << 4)));
            o1 = mfma32(pa, vf1, o1);
        }
        __syncthreads();
    }

    // lane l and l+32 cover complementary keys of qrow=q32: one xor finishes
    psum += __shfl_xor(psum, 32);
    float invown = 1.0f / psum;

#pragma unroll
    for (int r = 0; r < 16; ++r) {
        int rowl = (r & 3) + 8 * (r >> 2) + 4 * hi;
        float inv = __shfl(invown, rowl);
        int row = qb + wave * 32 + rowl;
        size_t base = (size_t)(b * 2048 + row) * 1024 + h * 64;
        ctx[base + q32]      = f2bf_bits(o0[r] * inv);
        ctx[base + 32 + q32] = f2bf_bits(o1[r] * inv);
    }
}

// ---------------------------------------------------------------------------
extern "C" void kernel_launch(void* const* d_in, const int* in_sizes, int n_in,
                              void* d_out, int out_size, void* d_ws, size_t ws_size,
                              hipStream_t stream)
{
    const float* q  = (const float*)d_in[0];
    const float* k  = (const float*)d_in[1];
    const float* v  = (const float*)d_in[2];
    const float* Wq = (const float*)d_in[3];
    const float* bq = (const float*)d_in[4];
    const float* Wk = (const float*)d_in[5];
    const float* bk = (const float*)d_in[6];
    const float* Wv = (const float*)d_in[7];
    const float* bv = (const float*)d_in[8];
    const float* Wo = (const float*)d_in[9];
    const float* bo = (const float*)d_in[10];
    float* out = (float*)d_out;

    char* ws = (char*)d_ws;
    const size_t SZ = (size_t)8192 * 1024 * 2; // 16 MiB per bf16 [M,D] buffer
    unsigned short* Qp = (unsigned short*)(ws);
    unsigned short* Kp = (unsigned short*)(ws + SZ);
    unsigned short* Vp = (unsigned short*)(ws + 2 * SZ);
    unsigned short* Vt = (unsigned short*)(ws + 3 * SZ);
    unsigned short* ctx = Vp;  // Vp dead after transpose; reuse for ctx
    unsigned short* Wbf = Vt;  // W bf16 parked in Vt region (dead until transpose)

    const float QSCALE = 0.1803368801111244f; // 0.125 * log2(e) for exp2 attn

    convert_w_kernel<<<dim3(1536), 256, 0, stream>>>(Wq, Wk, Wv, Wbf);

    dim3 gg(64, 8);
    gemm_bt_kernel<false, false><<<gg, 256, 0, stream>>>(q, Wbf,           bq, Qp, 8192, 1024, 1024, QSCALE);
    gemm_bt_kernel<false, false><<<gg, 256, 0, stream>>>(k, Wbf + 1048576, bk, Kp, 8192, 1024, 1024, 1.0f);
    gemm_bt_kernel<false, false><<<gg, 256, 0, stream>>>(v, Wbf + 2097152, bv, Vp, 8192, 1024, 1024, 1.0f);
    transpose_v_kernel<<<dim3(32, 64), 256, 0, stream>>>(Vp, Vt);
    attn_kernel<<<dim3(16, 64), 256, 0, stream>>>(Qp, Kp, Vt, ctx);
    gemm_bt_kernel<true, true><<<gg, 256, 0, stream>>>(ctx, Wo, bo, out, 8192, 1024, 1024, 1.0f);
}

// Round 14
// 222.055 us; speedup vs baseline: 1.0839x; 1.0448x over previous
//
#include <hip/hip_runtime.h>
#include <hip/hip_bf16.h>

typedef float   f32x4   __attribute__((ext_vector_type(4)));
typedef __bf16  bf16x8  __attribute__((ext_vector_type(8)));
typedef unsigned short u16x8 __attribute__((ext_vector_type(8)));
typedef unsigned short u16x4 __attribute__((ext_vector_type(4)));

#define DEVI __device__ __forceinline__

DEVI unsigned short f2bf_bits(float f) {
    __bf16 h = (__bf16)f;
    return __builtin_bit_cast(unsigned short, h);
}

DEVI f32x4 mfma_bf16(bf16x8 a, bf16x8 b, f32x4 c) {
    return __builtin_amdgcn_mfma_f32_16x16x32_bf16(a, b, c, 0, 0, 0);
}

// Native v_exp_f32 (2^x); log2(e) pre-folded into Q-projection scale.
DEVI float fast_exp2(float x) {
#if __has_builtin(__builtin_amdgcn_exp2f)
    return __builtin_amdgcn_exp2f(x);
#else
    float r;
    asm("v_exp_f32 %0, %1" : "=v"(r) : "v"(x));
    return r;
#endif
}

// Async global->LDS, 16B per lane; swizzle via pre-permuted global source.
DEVI void gload16(const void* g, void* l) {
    __builtin_amdgcn_global_load_lds(
        (const __attribute__((address_space(1))) void*)g,
        (__attribute__((address_space(3))) void*)l, 16, 0, 0);
}

// ---------------------------------------------------------------------------
// W f32->bf16 pre-convert (Wq,Wk,Wv -> contiguous bf16).
// ---------------------------------------------------------------------------
__global__ __launch_bounds__(256) void convert_w_kernel(
    const float* __restrict__ Wq, const float* __restrict__ Wk,
    const float* __restrict__ Wv, unsigned short* __restrict__ Wb)
{
    int idx = blockIdx.x * 256 + threadIdx.x;
    int which = idx >> 17;
    int off = (idx & 131071) * 8;
    const float* src = which == 0 ? Wq : (which == 1 ? Wk : Wv);
    f32x4 a = *(const f32x4*)(src + off);
    f32x4 b = *(const f32x4*)(src + off + 4);
    u16x8 h;
#pragma unroll
    for (int j = 0; j < 4; ++j) { h[j] = f2bf_bits(a[j]); h[4 + j] = f2bf_bits(b[j]); }
    *(u16x8*)(Wb + (size_t)which * 1048576 + off) = h;
}

// Wo f32->bf16 (runs after attn; parks in the then-dead Kp region).
__global__ __launch_bounds__(256) void convert_wo_kernel(
    const float* __restrict__ Wo, unsigned short* __restrict__ Wb)
{
    int off = (blockIdx.x * 256 + threadIdx.x) * 8;
    f32x4 a = *(const f32x4*)(Wo + off);
    f32x4 b = *(const f32x4*)(Wo + off + 4);
    u16x8 h;
#pragma unroll
    for (int j = 0; j < 4; ++j) { h[j] = f2bf_bits(a[j]); h[4 + j] = f2bf_bits(b[j]); }
    *(u16x8*)(Wb + off) = h;
}

// ---------------------------------------------------------------------------
// Projection GEMM: C[M,N] = A[M,K] @ W[N,K]^T + bias, scale on (val+bias).
// 128x128 tile, BK=64. W=bf16 via global_load_lds (pre-swizzled source);
// A=f32 T14 async-split reg-staging with inline bf16 convert. SPLIT dispatch
// per projection is structurally required (R5/R12: merged co-residency
// exceeds per-XCD L2 -> thrash).
// ---------------------------------------------------------------------------
__global__ __launch_bounds__(256) void proj_gemm_kernel(
    const float* __restrict__ Ap, const unsigned short* __restrict__ Wb,
    const float* __restrict__ bias, unsigned short* __restrict__ Cp,
    int M, int N, int K, float scale)
{
    __shared__ __align__(16) char ldsA[128 * 128];
    __shared__ __align__(16) char ldsB[128 * 128];
    const int t = threadIdx.x;
    const int wave = t >> 6, lane = t & 63;
    const int g = lane >> 4, c = lane & 15;
    const int rowbase = blockIdx.x * 128;
    const int colbase = blockIdx.y * 128;
    const int wr = (wave >> 1) * 64, wc = (wave & 1) * 64;

    const int arow = lane >> 3;
    const int aslot = (lane & 7) ^ arow;

    const float* fbase[4];
#pragma unroll
    for (int ch = 0; ch < 4; ++ch) {
        int id = ch * 256 + t;
        int row = id >> 3;
        int col = (id & 7) * 8;
        fbase[ch] = Ap + (size_t)(rowbase + row) * K + col;
    }

    f32x4 pre0[4], pre1[4];
#pragma unroll
    for (int ch = 0; ch < 4; ++ch) {
        pre0[ch] = *(const f32x4*)(fbase[ch]);
        pre1[ch] = *(const f32x4*)(fbase[ch] + 4);
    }

    f32x4 acc[4][4] = {};

    for (int kt = 0; kt < K; kt += 64) {
#pragma unroll
        for (int j = 0; j < 4; ++j) {
            int rg = wave * 4 + j;
            int row = rg * 8 + arow;
            gload16(Wb + (size_t)(colbase + row) * K + kt + aslot * 8,
                    ldsB + rg * 1024);
        }

#pragma unroll
        for (int ch = 0; ch < 4; ++ch) {
            int id = ch * 256 + t;
            int row = id >> 3;
            int col = (id & 7) * 8;
            int dst = row * 128 + ((col * 2) ^ ((row & 7) << 4));
            u16x8 hv;
#pragma unroll
            for (int j = 0; j < 4; ++j) { hv[j] = f2bf_bits(pre0[ch][j]); hv[4 + j] = f2bf_bits(pre1[ch][j]); }
            *(u16x8*)(ldsA + dst) = hv;
        }
        __syncthreads();

        if (kt + 64 < K) {
#pragma unroll
            for (int ch = 0; ch < 4; ++ch) {
                pre0[ch] = *(const f32x4*)(fbase[ch] + kt + 64);
                pre1[ch] = *(const f32x4*)(fbase[ch] + kt + 68);
            }
        }

#pragma unroll
        for (int kk = 0; kk < 2; ++kk) {
            bf16x8 af[4], bfr[4];
#pragma unroll
            for (int i = 0; i < 4; ++i) {
                int ra = wr + i * 16 + c;
                af[i] = *(const bf16x8*)(ldsA + ra * 128 + ((kk * 64 + g * 16) ^ ((ra & 7) << 4)));
                int rb = wc + i * 16 + c;
                bfr[i] = *(const bf16x8*)(ldsB + rb * 128 + ((kk * 64 + g * 16) ^ ((rb & 7) << 4)));
            }
#pragma unroll
            for (int i = 0; i < 4; ++i)
#pragma unroll
                for (int j = 0; j < 4; ++j)
                    acc[i][j] = mfma_bf16(af[i], bfr[j], acc[i][j]);
        }
        __syncthreads();
    }

#pragma unroll
    for (int j = 0; j < 4; ++j) {
        int coln = colbase + wc + j * 16 + c;
        float bv = bias[coln];
#pragma unroll
        for (int i = 0; i < 4; ++i) {
            int row0 = rowbase + wr + i * 16 + g * 4;
#pragma unroll
            for (int r = 0; r < 4; ++r) {
                float val = (acc[i][j][r] + bv) * scale;
                Cp[(size_t)(row0 + r) * N + coln] = f2bf_bits(val);
            }
        }
    }
}

// ---------------------------------------------------------------------------
// Output projection GEMM: BOTH operands bf16 via global_load_lds (m97
// structure, zero staging VALU). A=ctx bf16, W=Wo pre-converted bf16.
// ---------------------------------------------------------------------------
__global__ __launch_bounds__(256) void out_gemm_kernel(
    const unsigned short* __restrict__ Ab, const unsigned short* __restrict__ Wb,
    const float* __restrict__ bias, float* __restrict__ Cp,
    int M, int N, int K)
{
    __shared__ __align__(16) char ldsA[128 * 128];
    __shared__ __align__(16) char ldsB[128 * 128];
    const int t = threadIdx.x;
    const int wave = t >> 6, lane = t & 63;
    const int g = lane >> 4, c = lane & 15;
    const int rowbase = blockIdx.x * 128;
    const int colbase = blockIdx.y * 128;
    const int wr = (wave >> 1) * 64, wc = (wave & 1) * 64;

    const int arow = lane >> 3;
    const int aslot = (lane & 7) ^ arow;

    f32x4 acc[4][4] = {};

    for (int kt = 0; kt < K; kt += 64) {
#pragma unroll
        for (int j = 0; j < 4; ++j) {
            int rg = wave * 4 + j;
            int row = rg * 8 + arow;
            gload16(Ab + (size_t)(rowbase + row) * K + kt + aslot * 8,
                    ldsA + rg * 1024);
            gload16(Wb + (size_t)(colbase + row) * K + kt + aslot * 8,
                    ldsB + rg * 1024);
        }
        __syncthreads();

#pragma unroll
        for (int kk = 0; kk < 2; ++kk) {
            bf16x8 af[4], bfr[4];
#pragma unroll
            for (int i = 0; i < 4; ++i) {
                int ra = wr + i * 16 + c;
                af[i] = *(const bf16x8*)(ldsA + ra * 128 + ((kk * 64 + g * 16) ^ ((ra & 7) << 4)));
                int rb = wc + i * 16 + c;
                bfr[i] = *(const bf16x8*)(ldsB + rb * 128 + ((kk * 64 + g * 16) ^ ((rb & 7) << 4)));
            }
#pragma unroll
            for (int i = 0; i < 4; ++i)
#pragma unroll
                for (int j = 0; j < 4; ++j)
                    acc[i][j] = mfma_bf16(af[i], bfr[j], acc[i][j]);
        }
        __syncthreads();
    }

#pragma unroll
    for (int j = 0; j < 4; ++j) {
        int coln = colbase + wc + j * 16 + c;
        float bv = bias[coln];
#pragma unroll
        for (int i = 0; i < 4; ++i) {
            int row0 = rowbase + wr + i * 16 + g * 4;
#pragma unroll
            for (int r = 0; r < 4; ++r)
                Cp[(size_t)(row0 + r) * N + coln] = acc[i][j][r] + bv;
        }
    }
}

// ---------------------------------------------------------------------------
// Transpose Vp[B,S,D] (head-sliced) -> Vt[B,H,hd,S].
// ---------------------------------------------------------------------------
__global__ __launch_bounds__(256) void transpose_v_kernel(
    const unsigned short* __restrict__ Vp, unsigned short* __restrict__ Vt)
{
    __shared__ unsigned short tile[64][72];
    const int t = threadIdx.x;
    const int bh = blockIdx.y, b = bh >> 4, h = bh & 15;
    const int s0 = blockIdx.x * 64;
#pragma unroll
    for (int ch = 0; ch < 2; ++ch) {
        int id = ch * 256 + t;
        int srow = id >> 3, dcol = (id & 7) * 8;
        u16x8 v = *(const u16x8*)(Vp + (size_t)(b * 2048 + s0 + srow) * 1024 + h * 64 + dcol);
        *(u16x8*)&tile[srow][dcol] = v;
    }
    __syncthreads();
#pragma unroll
    for (int ch = 0; ch < 2; ++ch) {
        int id = ch * 256 + t;
        int drow = id >> 3, scol = (id & 7) * 8;
        u16x8 ov;
#pragma unroll
        for (int j = 0; j < 8; ++j) ov[j] = tile[scol + j][drow];
        *(u16x8*)(Vt + (size_t)(bh * 64 + drow) * 2048 + s0 + scol) = ov;
    }
}

// ---------------------------------------------------------------------------
// Flash attention — R10 version (known-good 98.8us; beats R13's 32x32
// in-register-P variant whose LDS-traffic win was cancelled by doubled bank
// conflicts + VALU shift). Grid (S/128, B*H) = 1024 blocks = 4/CU.
// 4 waves x 32 q-rows (2 q-sets). P = fast_exp2(S); fixed-max softmax;
// swapped QK^T; packed P writes; async-STAGE prefetch. No setprio (R6).
// ---------------------------------------------------------------------------
__global__ __launch_bounds__(256) void attn_kernel(
    const unsigned short* __restrict__ Qp, const unsigned short* __restrict__ Kp,
    const unsigned short* __restrict__ Vt, unsigned short* __restrict__ ctx)
{
    __shared__ __align__(16) char ldsK[64 * 128];
    __shared__ __align__(16) char ldsV[64 * 128];
    __shared__ __align__(16) char ldsP[4][2][16 * 128];
    const int t = threadIdx.x;
    const int wave = t >> 6, lane = t & 63;
    const int g = lane >> 4, c = lane & 15;
    const int bh = blockIdx.y, b = bh >> 4, h = bh & 15;
    const int qb = blockIdx.x * 128;

    bf16x8 qf0[2], qf1[2];
    {
        const unsigned short* q0 = Qp + (size_t)(b * 2048 + qb + wave * 32 + c) * 1024 + h * 64;
        qf0[0] = *(const bf16x8*)(q0 + 8 * g);
        qf0[1] = *(const bf16x8*)(q0 + 32 + 8 * g);
        const unsigned short* q1 = q0 + (size_t)16 * 1024;
        qf1[0] = *(const bf16x8*)(q1 + 8 * g);
        qf1[1] = *(const bf16x8*)(q1 + 32 + 8 * g);
    }

    f32x4 o0[4] = {}, o1[4] = {};
    float psum0 = 0.f, psum1 = 0.f;

    const int row0 = t >> 3, colB = (t & 7) * 8;
    const int row1 = 32 + row0;
    const int dst0 = row0 * 128 + ((colB * 2) ^ ((row0 & 7) << 4));
    const int dst1 = row1 * 128 + ((colB * 2) ^ ((row1 & 7) << 4));
    const unsigned short* Ksrc = Kp + (size_t)(b * 2048) * 1024 + h * 64;
    const unsigned short* Vsrc = Vt + (size_t)(bh * 64) * 2048;

    u16x8 kv0 = *(const u16x8*)(Ksrc + (size_t)row0 * 1024 + colB);
    u16x8 kv1 = *(const u16x8*)(Ksrc + (size_t)row1 * 1024 + colB);
    u16x8 vv0 = *(const u16x8*)(Vsrc + (size_t)row0 * 2048 + colB);
    u16x8 vv1 = *(const u16x8*)(Vsrc + (size_t)row1 * 2048 + colB);

    char* pw0 = ldsP[wave][0];
    char* pw1 = ldsP[wave][1];

    for (int kb = 0; kb < 2048; kb += 64) {
        *(u16x8*)(ldsK + dst0) = kv0;
        *(u16x8*)(ldsK + dst1) = kv1;
        *(u16x8*)(ldsV + dst0) = vv0;
        *(u16x8*)(ldsV + dst1) = vv1;
        __syncthreads();

        if (kb + 64 < 2048) {
            kv0 = *(const u16x8*)(Ksrc + (size_t)(kb + 64 + row0) * 1024 + colB);
            kv1 = *(const u16x8*)(Ksrc + (size_t)(kb + 64 + row1) * 1024 + colB);
            vv0 = *(const u16x8*)(Vsrc + (size_t)row0 * 2048 + kb + 64 + colB);
            vv1 = *(const u16x8*)(Vsrc + (size_t)row1 * 2048 + kb + 64 + colB);
        }

        f32x4 s0[4] = {}, s1[4] = {};
#pragma unroll
        for (int kk = 0; kk < 2; ++kk) {
            bf16x8 kf[4];
#pragma unroll
            for (int ti = 0; ti < 4; ++ti) {
                int rk = ti * 16 + c;
                kf[ti] = *(const bf16x8*)(ldsK + rk * 128 + ((kk * 64 + g * 16) ^ ((rk & 7) << 4)));
            }
#pragma unroll
            for (int ti = 0; ti < 4; ++ti) {
                s0[ti] = mfma_bf16(kf[ti], qf0[kk], s0[ti]);
                s1[ti] = mfma_bf16(kf[ti], qf1[kk], s1[ti]);
            }
        }

#pragma unroll
        for (int ti = 0; ti < 4; ++ti) {
            float p0 = fast_exp2(s0[ti][0]);
            float p1 = fast_exp2(s0[ti][1]);
            float p2 = fast_exp2(s0[ti][2]);
            float p3 = fast_exp2(s0[ti][3]);
            psum0 += (p0 + p1) + (p2 + p3);
            u16x4 hp;
            hp[0] = f2bf_bits(p0); hp[1] = f2bf_bits(p1);
            hp[2] = f2bf_bits(p2); hp[3] = f2bf_bits(p3);
            *(u16x4*)(pw0 + c * 128 + ((ti * 32 + g * 8) ^ ((c & 7) << 4))) = hp;
        }
#pragma unroll
        for (int ti = 0; ti < 4; ++ti) {
            float p0 = fast_exp2(s1[ti][0]);
            float p1 = fast_exp2(s1[ti][1]);
            float p2 = fast_exp2(s1[ti][2]);
            float p3 = fast_exp2(s1[ti][3]);
            psum1 += (p0 + p1) + (p2 + p3);
            u16x4 hp;
            hp[0] = f2bf_bits(p0); hp[1] = f2bf_bits(p1);
            hp[2] = f2bf_bits(p2); hp[3] = f2bf_bits(p3);
            *(u16x4*)(pw1 + c * 128 + ((ti * 32 + g * 8) ^ ((c & 7) << 4))) = hp;
        }

#pragma unroll
        for (int kk = 0; kk < 2; ++kk) {
            bf16x8 vf[4];
#pragma unroll
            for (int ti = 0; ti < 4; ++ti) {
                int rv = ti * 16 + c;
                vf[ti] = *(const bf16x8*)(ldsV + rv * 128 + ((kk * 64 + g * 16) ^ ((rv & 7) << 4)));
            }
            bf16x8 pa0 = *(const bf16x8*)(pw0 + c * 128 + ((kk * 64 + g * 16) ^ ((c & 7) << 4)));
            bf16x8 pa1 = *(const bf16x8*)(pw1 + c * 128 + ((kk * 64 + g * 16) ^ ((c & 7) << 4)));
#pragma unroll
            for (int ti = 0; ti < 4; ++ti) {
                o0[ti] = mfma_bf16(pa0, vf[ti], o0[ti]);
                o1[ti] = mfma_bf16(pa1, vf[ti], o1[ti]);
            }
        }
        __syncthreads();
    }

    psum0 += __shfl_xor(psum0, 16);
    psum0 += __shfl_xor(psum0, 32);
    psum1 += __shfl_xor(psum1, 16);
    psum1 += __shfl_xor(psum1, 32);

#pragma unroll
    for (int r = 0; r < 4; ++r) {
        float inv0 = 1.0f / __shfl(psum0, 4 * g + r);
        float inv1 = 1.0f / __shfl(psum1, 4 * g + r);
        int row0q = qb + wave * 32 + 4 * g + r;
        int row1q = row0q + 16;
#pragma unroll
        for (int ti = 0; ti < 4; ++ti) {
            int col = h * 64 + ti * 16 + c;
            ctx[(size_t)(b * 2048 + row0q) * 1024 + col] = f2bf_bits(o0[ti][r] * inv0);
            ctx[(size_t)(b * 2048 + row1q) * 1024 + col] = f2bf_bits(o1[ti][r] * inv1);
        }
    }
}

// ---------------------------------------------------------------------------
extern "C" void kernel_launch(void* const* d_in, const int* in_sizes, int n_in,
                              void* d_out, int out_size, void* d_ws, size_t ws_size,
                              hipStream_t stream)
{
    const float* q  = (const float*)d_in[0];
    const float* k  = (const float*)d_in[1];
    const float* v  = (const float*)d_in[2];
    const float* Wq = (const float*)d_in[3];
    const float* bq = (const float*)d_in[4];
    const float* Wk = (const float*)d_in[5];
    const float* bk = (const float*)d_in[6];
    const float* Wv = (const float*)d_in[7];
    const float* bv = (const float*)d_in[8];
    const float* Wo = (const float*)d_in[9];
    const float* bo = (const float*)d_in[10];
    float* out = (float*)d_out;

    char* ws = (char*)d_ws;
    const size_t SZ = (size_t)8192 * 1024 * 2; // 16 MiB per bf16 [M,D] buffer
    unsigned short* Qp = (unsigned short*)(ws);
    unsigned short* Kp = (unsigned short*)(ws + SZ);
    unsigned short* Vp = (unsigned short*)(ws + 2 * SZ);
    unsigned short* Vt = (unsigned short*)(ws + 3 * SZ);
    unsigned short* ctx = Vp;  // Vp dead after transpose; reuse for ctx
    unsigned short* Wbf = Vt;  // W bf16 parked in Vt region (dead until transpose)
    unsigned short* Wob = Kp;  // Wo bf16 parked in Kp region (dead after attn)

    const float QSCALE = 0.1803368801111244f; // 0.125 * log2(e) for exp2 attn

    convert_w_kernel<<<dim3(1536), 256, 0, stream>>>(Wq, Wk, Wv, Wbf);

    dim3 gg(64, 8);
    proj_gemm_kernel<<<gg, 256, 0, stream>>>(q, Wbf,           bq, Qp, 8192, 1024, 1024, QSCALE);
    proj_gemm_kernel<<<gg, 256, 0, stream>>>(k, Wbf + 1048576, bk, Kp, 8192, 1024, 1024, 1.0f);
    proj_gemm_kernel<<<gg, 256, 0, stream>>>(v, Wbf + 2097152, bv, Vp, 8192, 1024, 1024, 1.0f);
    transpose_v_kernel<<<dim3(32, 64), 256, 0, stream>>>(Vp, Vt);
    attn_kernel<<<dim3(16, 64), 256, 0, stream>>>(Qp, Kp, Vt, ctx);
    convert_wo_kernel<<<dim3(512), 256, 0, stream>>>(Wo, Wob);
    out_gemm_kernel<<<gg, 256, 0, stream>>>(ctx, Wob, bo, out, 8192, 1024, 1024);
}

// Round 15
// 215.734 us; speedup vs baseline: 1.1157x; 1.0293x over previous
//
#include <hip/hip_runtime.h>
#include <hip/hip_bf16.h>

typedef float   f32x4   __attribute__((ext_vector_type(4)));
typedef __bf16  bf16x8  __attribute__((ext_vector_type(8)));
typedef unsigned short u16x8 __attribute__((ext_vector_type(8)));
typedef unsigned short u16x4 __attribute__((ext_vector_type(4)));

#define DEVI __device__ __forceinline__

DEVI unsigned short f2bf_bits(float f) {
    __bf16 h = (__bf16)f;
    return __builtin_bit_cast(unsigned short, h);
}

DEVI f32x4 mfma_bf16(bf16x8 a, bf16x8 b, f32x4 c) {
    return __builtin_amdgcn_mfma_f32_16x16x32_bf16(a, b, c, 0, 0, 0);
}

// Native v_exp_f32 (2^x); log2(e) pre-folded into Q-projection scale.
DEVI float fast_exp2(float x) {
#if __has_builtin(__builtin_amdgcn_exp2f)
    return __builtin_amdgcn_exp2f(x);
#else
    float r;
    asm("v_exp_f32 %0, %1" : "=v"(r) : "v"(x));
    return r;
#endif
}

// Async global->LDS, 16B per lane; swizzle via pre-permuted global source.
DEVI void gload16(const void* g, void* l) {
    __builtin_amdgcn_global_load_lds(
        (const __attribute__((address_space(1))) void*)g,
        (__attribute__((address_space(3))) void*)l, 16, 0, 0);
}

// ---------------------------------------------------------------------------
// W f32->bf16 pre-convert (Wq,Wk,Wv -> contiguous bf16).
// ---------------------------------------------------------------------------
__global__ __launch_bounds__(256) void convert_w_kernel(
    const float* __restrict__ Wq, const float* __restrict__ Wk,
    const float* __restrict__ Wv, unsigned short* __restrict__ Wb)
{
    int idx = blockIdx.x * 256 + threadIdx.x;
    int which = idx >> 17;
    int off = (idx & 131071) * 8;
    const float* src = which == 0 ? Wq : (which == 1 ? Wk : Wv);
    f32x4 a = *(const f32x4*)(src + off);
    f32x4 b = *(const f32x4*)(src + off + 4);
    u16x8 h;
#pragma unroll
    for (int j = 0; j < 4; ++j) { h[j] = f2bf_bits(a[j]); h[4 + j] = f2bf_bits(b[j]); }
    *(u16x8*)(Wb + (size_t)which * 1048576 + off) = h;
}

// Wo f32->bf16 (runs after attn; parks in the then-dead Kp region).
__global__ __launch_bounds__(256) void convert_wo_kernel(
    const float* __restrict__ Wo, unsigned short* __restrict__ Wb)
{
    int off = (blockIdx.x * 256 + threadIdx.x) * 8;
    f32x4 a = *(const f32x4*)(Wo + off);
    f32x4 b = *(const f32x4*)(Wo + off + 4);
    u16x8 h;
#pragma unroll
    for (int j = 0; j < 4; ++j) { h[j] = f2bf_bits(a[j]); h[4 + j] = f2bf_bits(b[j]); }
    *(u16x8*)(Wb + off) = h;
}

// ---------------------------------------------------------------------------
// Projection GEMM: C[M,N] = A[M,K] @ W[N,K]^T + bias, scale on (val+bias).
// 128x128 tile, BK=64. W=bf16 via global_load_lds (pre-swizzled source);
// A=f32 T14 async-split reg-staging with inline bf16 convert. SPLIT dispatch
// per projection is structurally required (R5/R12: merged co-residency
// exceeds per-XCD L2 -> thrash).
// ---------------------------------------------------------------------------
__global__ __launch_bounds__(256) void proj_gemm_kernel(
    const float* __restrict__ Ap, const unsigned short* __restrict__ Wb,
    const float* __restrict__ bias, unsigned short* __restrict__ Cp,
    int M, int N, int K, float scale)
{
    __shared__ __align__(16) char ldsA[128 * 128];
    __shared__ __align__(16) char ldsB[128 * 128];
    const int t = threadIdx.x;
    const int wave = t >> 6, lane = t & 63;
    const int g = lane >> 4, c = lane & 15;
    const int rowbase = blockIdx.x * 128;
    const int colbase = blockIdx.y * 128;
    const int wr = (wave >> 1) * 64, wc = (wave & 1) * 64;

    const int arow = lane >> 3;
    const int aslot = (lane & 7) ^ arow;

    const float* fbase[4];
#pragma unroll
    for (int ch = 0; ch < 4; ++ch) {
        int id = ch * 256 + t;
        int row = id >> 3;
        int col = (id & 7) * 8;
        fbase[ch] = Ap + (size_t)(rowbase + row) * K + col;
    }

    f32x4 pre0[4], pre1[4];
#pragma unroll
    for (int ch = 0; ch < 4; ++ch) {
        pre0[ch] = *(const f32x4*)(fbase[ch]);
        pre1[ch] = *(const f32x4*)(fbase[ch] + 4);
    }

    f32x4 acc[4][4] = {};

    for (int kt = 0; kt < K; kt += 64) {
#pragma unroll
        for (int j = 0; j < 4; ++j) {
            int rg = wave * 4 + j;
            int row = rg * 8 + arow;
            gload16(Wb + (size_t)(colbase + row) * K + kt + aslot * 8,
                    ldsB + rg * 1024);
        }

#pragma unroll
        for (int ch = 0; ch < 4; ++ch) {
            int id = ch * 256 + t;
            int row = id >> 3;
            int col = (id & 7) * 8;
            int dst = row * 128 + ((col * 2) ^ ((row & 7) << 4));
            u16x8 hv;
#pragma unroll
            for (int j = 0; j < 4; ++j) { hv[j] = f2bf_bits(pre0[ch][j]); hv[4 + j] = f2bf_bits(pre1[ch][j]); }
            *(u16x8*)(ldsA + dst) = hv;
        }
        __syncthreads();

        if (kt + 64 < K) {
#pragma unroll
            for (int ch = 0; ch < 4; ++ch) {
                pre0[ch] = *(const f32x4*)(fbase[ch] + kt + 64);
                pre1[ch] = *(const f32x4*)(fbase[ch] + kt + 68);
            }
        }

#pragma unroll
        for (int kk = 0; kk < 2; ++kk) {
            bf16x8 af[4], bfr[4];
#pragma unroll
            for (int i = 0; i < 4; ++i) {
                int ra = wr + i * 16 + c;
                af[i] = *(const bf16x8*)(ldsA + ra * 128 + ((kk * 64 + g * 16) ^ ((ra & 7) << 4)));
                int rb = wc + i * 16 + c;
                bfr[i] = *(const bf16x8*)(ldsB + rb * 128 + ((kk * 64 + g * 16) ^ ((rb & 7) << 4)));
            }
#pragma unroll
            for (int i = 0; i < 4; ++i)
#pragma unroll
                for (int j = 0; j < 4; ++j)
                    acc[i][j] = mfma_bf16(af[i], bfr[j], acc[i][j]);
        }
        __syncthreads();
    }

#pragma unroll
    for (int j = 0; j < 4; ++j) {
        int coln = colbase + wc + j * 16 + c;
        float bv = bias[coln];
#pragma unroll
        for (int i = 0; i < 4; ++i) {
            int row0 = rowbase + wr + i * 16 + g * 4;
#pragma unroll
            for (int r = 0; r < 4; ++r) {
                float val = (acc[i][j][r] + bv) * scale;
                Cp[(size_t)(row0 + r) * N + coln] = f2bf_bits(val);
            }
        }
    }
}

// ---------------------------------------------------------------------------
// Output projection GEMM: BOTH operands bf16 via global_load_lds.
// ---------------------------------------------------------------------------
__global__ __launch_bounds__(256) void out_gemm_kernel(
    const unsigned short* __restrict__ Ab, const unsigned short* __restrict__ Wb,
    const float* __restrict__ bias, float* __restrict__ Cp,
    int M, int N, int K)
{
    __shared__ __align__(16) char ldsA[128 * 128];
    __shared__ __align__(16) char ldsB[128 * 128];
    const int t = threadIdx.x;
    const int wave = t >> 6, lane = t & 63;
    const int g = lane >> 4, c = lane & 15;
    const int rowbase = blockIdx.x * 128;
    const int colbase = blockIdx.y * 128;
    const int wr = (wave >> 1) * 64, wc = (wave & 1) * 64;

    const int arow = lane >> 3;
    const int aslot = (lane & 7) ^ arow;

    f32x4 acc[4][4] = {};

    for (int kt = 0; kt < K; kt += 64) {
#pragma unroll
        for (int j = 0; j < 4; ++j) {
            int rg = wave * 4 + j;
            int row = rg * 8 + arow;
            gload16(Ab + (size_t)(rowbase + row) * K + kt + aslot * 8,
                    ldsA + rg * 1024);
            gload16(Wb + (size_t)(colbase + row) * K + kt + aslot * 8,
                    ldsB + rg * 1024);
        }
        __syncthreads();

#pragma unroll
        for (int kk = 0; kk < 2; ++kk) {
            bf16x8 af[4], bfr[4];
#pragma unroll
            for (int i = 0; i < 4; ++i) {
                int ra = wr + i * 16 + c;
                af[i] = *(const bf16x8*)(ldsA + ra * 128 + ((kk * 64 + g * 16) ^ ((ra & 7) << 4)));
                int rb = wc + i * 16 + c;
                bfr[i] = *(const bf16x8*)(ldsB + rb * 128 + ((kk * 64 + g * 16) ^ ((rb & 7) << 4)));
            }
#pragma unroll
            for (int i = 0; i < 4; ++i)
#pragma unroll
                for (int j = 0; j < 4; ++j)
                    acc[i][j] = mfma_bf16(af[i], bfr[j], acc[i][j]);
        }
        __syncthreads();
    }

#pragma unroll
    for (int j = 0; j < 4; ++j) {
        int coln = colbase + wc + j * 16 + c;
        float bv = bias[coln];
#pragma unroll
        for (int i = 0; i < 4; ++i) {
            int row0 = rowbase + wr + i * 16 + g * 4;
#pragma unroll
            for (int r = 0; r < 4; ++r)
                Cp[(size_t)(row0 + r) * N + coln] = acc[i][j][r] + bv;
        }
    }
}

// ---------------------------------------------------------------------------
// Transpose Vp[B,S,D] (head-sliced) -> Vt[B,H,hd,S].
// ---------------------------------------------------------------------------
__global__ __launch_bounds__(256) void transpose_v_kernel(
    const unsigned short* __restrict__ Vp, unsigned short* __restrict__ Vt)
{
    __shared__ unsigned short tile[64][72];
    const int t = threadIdx.x;
    const int bh = blockIdx.y, b = bh >> 4, h = bh & 15;
    const int s0 = blockIdx.x * 64;
#pragma unroll
    for (int ch = 0; ch < 2; ++ch) {
        int id = ch * 256 + t;
        int srow = id >> 3, dcol = (id & 7) * 8;
        u16x8 v = *(const u16x8*)(Vp + (size_t)(b * 2048 + s0 + srow) * 1024 + h * 64 + dcol);
        *(u16x8*)&tile[srow][dcol] = v;
    }
    __syncthreads();
#pragma unroll
    for (int ch = 0; ch < 2; ++ch) {
        int id = ch * 256 + t;
        int drow = id >> 3, scol = (id & 7) * 8;
        u16x8 ov;
#pragma unroll
        for (int j = 0; j < 8; ++j) ov[j] = tile[scol + j][drow];
        *(u16x8*)(Vt + (size_t)(bh * 64 + drow) * 2048 + s0 + scol) = ov;
    }
}

// ---------------------------------------------------------------------------
// Flash attention. R14 post-mortem corrected the arithmetic: LDS traffic is
// 3.67GB (~53% of ceiling), no pipe >60% busy -> LATENCY/OCCUPANCY-bound,
// not LDS-BW-bound. Two levers here:
//  1. P-sequential PV: one 2KB P buffer per wave, qset0 exp->write->PV then
//     qset1. ldsP 16->8KB, block LDS 32->24KB -> LDS-capped residency
//     5->6 blocks/CU. Cost: V-frags read twice (traffic 112->144KB/tile,
//     still under the BW ceiling).
//  2. XCD-grouped mapping: 1D grid 1024; xcd=bid&7 gets heads [8*xcd,8*xcd+8)
//     -> per-XCD K/V working set 4MB (L2-fit) instead of all 64 heads ->
//     staging prefetch covered by L2 latency.
// P = fast_exp2(S); fixed-max softmax; swapped QK^T; packed P writes;
// async-STAGE prefetch. No setprio (R6).
// ---------------------------------------------------------------------------
__global__ __launch_bounds__(256) void attn_kernel(
    const unsigned short* __restrict__ Qp, const unsigned short* __restrict__ Kp,
    const unsigned short* __restrict__ Vt, unsigned short* __restrict__ ctx)
{
    __shared__ __align__(16) char ldsK[64 * 128];
    __shared__ __align__(16) char ldsV[64 * 128];
    __shared__ __align__(16) char ldsP[4][16 * 128];   // one 2KB buffer/wave
    const int t = threadIdx.x;
    const int wave = t >> 6, lane = t & 63;
    const int g = lane >> 4, c = lane & 15;

    // XCD-grouped decode: xcd d&7 owns heads [8*xcd, 8*xcd+8)
    const int d = blockIdx.x;
    const int slot = d >> 3;
    const int bh = (d & 7) * 8 + (slot >> 4);
    const int qblk = slot & 15;
    const int b = bh >> 4, h = bh & 15;
    const int qb = qblk * 128;

    bf16x8 qf0[2], qf1[2];
    {
        const unsigned short* q0 = Qp + (size_t)(b * 2048 + qb + wave * 32 + c) * 1024 + h * 64;
        qf0[0] = *(const bf16x8*)(q0 + 8 * g);
        qf0[1] = *(const bf16x8*)(q0 + 32 + 8 * g);
        const unsigned short* q1 = q0 + (size_t)16 * 1024;
        qf1[0] = *(const bf16x8*)(q1 + 8 * g);
        qf1[1] = *(const bf16x8*)(q1 + 32 + 8 * g);
    }

    f32x4 o0[4] = {}, o1[4] = {};
    float psum0 = 0.f, psum1 = 0.f;

    const int row0 = t >> 3, colB = (t & 7) * 8;
    const int row1 = 32 + row0;
    const int dst0 = row0 * 128 + ((colB * 2) ^ ((row0 & 7) << 4));
    const int dst1 = row1 * 128 + ((colB * 2) ^ ((row1 & 7) << 4));
    const unsigned short* Ksrc = Kp + (size_t)(b * 2048) * 1024 + h * 64;
    const unsigned short* Vsrc = Vt + (size_t)(bh * 64) * 2048;

    u16x8 kv0 = *(const u16x8*)(Ksrc + (size_t)row0 * 1024 + colB);
    u16x8 kv1 = *(const u16x8*)(Ksrc + (size_t)row1 * 1024 + colB);
    u16x8 vv0 = *(const u16x8*)(Vsrc + (size_t)row0 * 2048 + colB);
    u16x8 vv1 = *(const u16x8*)(Vsrc + (size_t)row1 * 2048 + colB);

    char* pw = ldsP[wave];

    for (int kb = 0; kb < 2048; kb += 64) {
        *(u16x8*)(ldsK + dst0) = kv0;
        *(u16x8*)(ldsK + dst1) = kv1;
        *(u16x8*)(ldsV + dst0) = vv0;
        *(u16x8*)(ldsV + dst1) = vv1;
        __syncthreads();

        if (kb + 64 < 2048) {
            kv0 = *(const u16x8*)(Ksrc + (size_t)(kb + 64 + row0) * 1024 + colB);
            kv1 = *(const u16x8*)(Ksrc + (size_t)(kb + 64 + row1) * 1024 + colB);
            vv0 = *(const u16x8*)(Vsrc + (size_t)row0 * 2048 + kb + 64 + colB);
            vv1 = *(const u16x8*)(Vsrc + (size_t)row1 * 2048 + kb + 64 + colB);
        }

        // S^T = K Q^T for both q-sets; K-frags read once, used twice
        f32x4 s0[4] = {}, s1[4] = {};
#pragma unroll
        for (int kk = 0; kk < 2; ++kk) {
            bf16x8 kf[4];
#pragma unroll
            for (int ti = 0; ti < 4; ++ti) {
                int rk = ti * 16 + c;
                kf[ti] = *(const bf16x8*)(ldsK + rk * 128 + ((kk * 64 + g * 16) ^ ((rk & 7) << 4)));
            }
#pragma unroll
            for (int ti = 0; ti < 4; ++ti) {
                s0[ti] = mfma_bf16(kf[ti], qf0[kk], s0[ti]);
                s1[ti] = mfma_bf16(kf[ti], qf1[kk], s1[ti]);
            }
        }

        // ---- q-set 0: exp -> P write -> PV (single shared P buffer) ----
#pragma unroll
        for (int ti = 0; ti < 4; ++ti) {
            float p0 = fast_exp2(s0[ti][0]);
            float p1 = fast_exp2(s0[ti][1]);
            float p2 = fast_exp2(s0[ti][2]);
            float p3 = fast_exp2(s0[ti][3]);
            psum0 += (p0 + p1) + (p2 + p3);
            u16x4 hp;
            hp[0] = f2bf_bits(p0); hp[1] = f2bf_bits(p1);
            hp[2] = f2bf_bits(p2); hp[3] = f2bf_bits(p3);
            *(u16x4*)(pw + c * 128 + ((ti * 32 + g * 8) ^ ((c & 7) << 4))) = hp;
        }
#pragma unroll
        for (int kk = 0; kk < 2; ++kk) {
            bf16x8 vf[4];
#pragma unroll
            for (int ti = 0; ti < 4; ++ti) {
                int rv = ti * 16 + c;
                vf[ti] = *(const bf16x8*)(ldsV + rv * 128 + ((kk * 64 + g * 16) ^ ((rv & 7) << 4)));
            }
            bf16x8 pa = *(const bf16x8*)(pw + c * 128 + ((kk * 64 + g * 16) ^ ((c & 7) << 4)));
#pragma unroll
            for (int ti = 0; ti < 4; ++ti)
                o0[ti] = mfma_bf16(pa, vf[ti], o0[ti]);
        }

        // ---- q-set 1: exp -> P write (overwrite) -> PV ----
#pragma unroll
        for (int ti = 0; ti < 4; ++ti) {
            float p0 = fast_exp2(s1[ti][0]);
            float p1 = fast_exp2(s1[ti][1]);
            float p2 = fast_exp2(s1[ti][2]);
            float p3 = fast_exp2(s1[ti][3]);
            psum1 += (p0 + p1) + (p2 + p3);
            u16x4 hp;
            hp[0] = f2bf_bits(p0); hp[1] = f2bf_bits(p1);
            hp[2] = f2bf_bits(p2); hp[3] = f2bf_bits(p3);
            *(u16x4*)(pw + c * 128 + ((ti * 32 + g * 8) ^ ((c & 7) << 4))) = hp;
        }
#pragma unroll
        for (int kk = 0; kk < 2; ++kk) {
            bf16x8 vf[4];
#pragma unroll
            for (int ti = 0; ti < 4; ++ti) {
                int rv = ti * 16 + c;
                vf[ti] = *(const bf16x8*)(ldsV + rv * 128 + ((kk * 64 + g * 16) ^ ((rv & 7) << 4)));
            }
            bf16x8 pa = *(const bf16x8*)(pw + c * 128 + ((kk * 64 + g * 16) ^ ((c & 7) << 4)));
#pragma unroll
            for (int ti = 0; ti < 4; ++ti)
                o1[ti] = mfma_bf16(pa, vf[ti], o1[ti]);
        }
        __syncthreads();
    }

    psum0 += __shfl_xor(psum0, 16);
    psum0 += __shfl_xor(psum0, 32);
    psum1 += __shfl_xor(psum1, 16);
    psum1 += __shfl_xor(psum1, 32);

#pragma unroll
    for (int r = 0; r < 4; ++r) {
        float inv0 = 1.0f / __shfl(psum0, 4 * g + r);
        float inv1 = 1.0f / __shfl(psum1, 4 * g + r);
        int row0q = qb + wave * 32 + 4 * g + r;
        int row1q = row0q + 16;
#pragma unroll
        for (int ti = 0; ti < 4; ++ti) {
            int col = h * 64 + ti * 16 + c;
            ctx[(size_t)(b * 2048 + row0q) * 1024 + col] = f2bf_bits(o0[ti][r] * inv0);
            ctx[(size_t)(b * 2048 + row1q) * 1024 + col] = f2bf_bits(o1[ti][r] * inv1);
        }
    }
}

// ---------------------------------------------------------------------------
extern "C" void kernel_launch(void* const* d_in, const int* in_sizes, int n_in,
                              void* d_out, int out_size, void* d_ws, size_t ws_size,
                              hipStream_t stream)
{
    const float* q  = (const float*)d_in[0];
    const float* k  = (const float*)d_in[1];
    const float* v  = (const float*)d_in[2];
    const float* Wq = (const float*)d_in[3];
    const float* bq = (const float*)d_in[4];
    const float* Wk = (const float*)d_in[5];
    const float* bk = (const float*)d_in[6];
    const float* Wv = (const float*)d_in[7];
    const float* bv = (const float*)d_in[8];
    const float* Wo = (const float*)d_in[9];
    const float* bo = (const float*)d_in[10];
    float* out = (float*)d_out;

    char* ws = (char*)d_ws;
    const size_t SZ = (size_t)8192 * 1024 * 2; // 16 MiB per bf16 [M,D] buffer
    unsigned short* Qp = (unsigned short*)(ws);
    unsigned short* Kp = (unsigned short*)(ws + SZ);
    unsigned short* Vp = (unsigned short*)(ws + 2 * SZ);
    unsigned short* Vt = (unsigned short*)(ws + 3 * SZ);
    unsigned short* ctx = Vp;  // Vp dead after transpose; reuse for ctx
    unsigned short* Wbf = Vt;  // W bf16 parked in Vt region (dead until transpose)
    unsigned short* Wob = Kp;  // Wo bf16 parked in Kp region (dead after attn)

    const float QSCALE = 0.1803368801111244f; // 0.125 * log2(e) for exp2 attn

    convert_w_kernel<<<dim3(1536), 256, 0, stream>>>(Wq, Wk, Wv, Wbf);

    dim3 gg(64, 8);
    proj_gemm_kernel<<<gg, 256, 0, stream>>>(q, Wbf,           bq, Qp, 8192, 1024, 1024, QSCALE);
    proj_gemm_kernel<<<gg, 256, 0, stream>>>(k, Wbf + 1048576, bk, Kp, 8192, 1024, 1024, 1.0f);
    proj_gemm_kernel<<<gg, 256, 0, stream>>>(v, Wbf + 2097152, bv, Vp, 8192, 1024, 1024, 1.0f);
    transpose_v_kernel<<<dim3(32, 64), 256, 0, stream>>>(Vp, Vt);
    attn_kernel<<<dim3(1024), 256, 0, stream>>>(Qp, Kp, Vt, ctx);
    convert_wo_kernel<<<dim3(512), 256, 0, stream>>>(Wo, Wob);
    out_gemm_kernel<<<gg, 256, 0, stream>>>(ctx, Wob, bo, out, 8192, 1024, 1024);
}